// Round 15
// baseline (191.054 us; speedup 1.0000x reference)
//
#include <hip/hip_runtime.h>
#include <hip/hip_bf16.h>
#include <hip/hip_fp16.h>
#include <math.h>

// Problem constants: B=8, C=256, H=W=64, J=17, Hd=4, dim=3
#define HH 64
#define WW 64
#define HW 4096
#define CC 256
#define BB 8
#define JJ 17

typedef __attribute__((ext_vector_type(8))) short bf16x8;
typedef __attribute__((ext_vector_type(8))) _Float16 f16x8;
typedef __attribute__((ext_vector_type(4))) float f32x4;

#define SLD 264    // dcn LDS row stride (shorts): additive (row+granule)%8 spread is conflict-minimal
#define SLDF 266   // fused_tail stride (shorts)
#define CST 136    // conv3x3 strip c-stride in shorts
#define TLD 266    // transpose LDS stride in shorts

struct Bil { int i00,i01,i10,i11; float w00,w01,w10,w11; };

__device__ inline Bil bilin(float sx, float sy) {
    float x0f = floorf(sx), y0f = floorf(sy);
    float wx1 = sx - x0f, wy1 = sy - y0f;
    float wx0 = 1.f - wx1, wy0 = 1.f - wy1;
    int x0 = (int)x0f, y0 = (int)y0f;
    int x1 = x0 + 1, y1 = y0 + 1;
    bool vx0 = (unsigned)x0 < (unsigned)WW;
    bool vx1 = (unsigned)x1 < (unsigned)WW;
    bool vy0 = (unsigned)y0 < (unsigned)HH;
    bool vy1 = (unsigned)y1 < (unsigned)HH;
    int x0c = min(max(x0,0),WW-1), x1c = min(max(x1,0),WW-1);
    int y0c = min(max(y0,0),HH-1), y1c = min(max(y1,0),HH-1);
    Bil b;
    b.i00 = y0c*WW + x0c; b.i01 = y0c*WW + x1c;
    b.i10 = y1c*WW + x0c; b.i11 = y1c*WW + x1c;
    b.w00 = wx0*wy0*((vx0&&vy0)?1.f:0.f);
    b.w01 = wx1*wy0*((vx1&&vy0)?1.f:0.f);
    b.w10 = wx0*wy1*((vx0&&vy1)?1.f:0.f);
    b.w11 = wx1*wy1*((vx1&&vy1)?1.f:0.f);
    return b;
}

__device__ inline unsigned short f2bf(float f) {
    unsigned u = __float_as_uint(f);
    unsigned r = (u + 0x7fffu + ((u >> 16) & 1u)) >> 16;
    return (unsigned short)r;
}
__device__ inline unsigned short f2h(float f) {
    return __half_as_ushort(__float2half(f));
}
__device__ inline unsigned cvt_pk_bf16(float lo, float hi) {
    unsigned r;
    asm("v_cvt_pk_bf16_f32 %0, %1, %2" : "=v"(r) : "v"(lo), "v"(hi));
    return r;
}
__device__ inline float bflo(unsigned u) { return __uint_as_float(u << 16); }
__device__ inline float bfhi(unsigned u) { return __uint_as_float(u & 0xFFFF0000u); }
__device__ inline float bf2f(unsigned short us) { return __uint_as_float(((unsigned)us) << 16); }
__device__ inline __half2 u2h2(unsigned u) { union { unsigned u; __half2 h; } c; c.u = u; return c.h; }
__device__ inline unsigned h22u(__half2 h) { union { unsigned u; __half2 h; } c; c.h = h; return c.u; }

struct F8 { float4 a, b; };
__device__ inline F8 ld8(const float* p) {
    F8 r; r.a = *(const float4*)p; r.b = *(const float4*)(p + 4); return r;
}
__device__ inline void gsample8(const float* base, const Bil& bl, float out[8]) {
    F8 v00 = ld8(base + (size_t)bl.i00*8);
    F8 v01 = ld8(base + (size_t)bl.i01*8);
    F8 v10 = ld8(base + (size_t)bl.i10*8);
    F8 v11 = ld8(base + (size_t)bl.i11*8);
    const float* p00 = (const float*)&v00;
    const float* p01 = (const float*)&v01;
    const float* p10 = (const float*)&v10;
    const float* p11 = (const float*)&v11;
    #pragma unroll
    for (int i = 0; i < 8; i++)
        out[i] = bl.w00*p00[i] + bl.w01*p01[i] + bl.w10*p10[i] + bl.w11*p11[i];
}

// K0: transpose feat (NCHW f32) -> featT (N,px,c) fp16.
__global__ __launch_bounds__(256) void nhwc_kernel(
        const float* __restrict__ feat, unsigned short* __restrict__ featT) {
    __shared__ unsigned short T[64*TLD];   // 34 KB
    int b = blockIdx.x >> 6, p0 = (blockIdx.x & 63)*64;
    int t = threadIdx.x;
    int x = t & 63, c4 = t >> 6;
    const float* fb = feat + (size_t)b*CC*HW + p0;
    #pragma unroll 4
    for (int cp = 0; cp < 256; cp += 4) {
        int c = cp + c4;
        T[x*TLD + c] = f2h(fb[(size_t)c*HW + x]);
    }
    __syncthreads();
    int xq = t >> 5, cl = t & 31;
    unsigned short* dst = featT + ((size_t)b*HW + p0)*256;
    #pragma unroll
    for (int w = 0; w < 8; w++) {
        int xr = w*8 + xq;
        *(uint4*)(dst + (size_t)xr*256 + cl*8) = *(const uint4*)(T + xr*TLD + cl*8);
    }
}

// K1a: pack dcn_off_w into MFMA A-fragment order, fp16.
__global__ void cpack_kernel(const float* __restrict__ w, short* __restrict__ Ap) {
    int idx = blockIdx.x*256 + threadIdx.x;   // 9216
    if (idx >= 9*2*8*64) return;
    int l  = idx & 63;
    int cs = (idx >> 6) & 7;
    int mt = (idx >> 9) & 1;
    int k  = idx >> 10;
    int oc = mt*16 + (l & 15);
    int c0 = cs*32 + (l >> 4)*8;
    short* dst = Ap + (size_t)idx*8;
    #pragma unroll
    for (int i = 0; i < 8; i++) {
        float v = (oc < 27) ? w[((size_t)(oc*256 + c0 + i)*3 + k/3)*3 + (k % 3)] : 0.f;
        dst[i] = (short)f2h(v);
    }
}

// K1: 3x3 conv featT (fp16) -> off27 via MFMA on a 3-row strip.
__global__ __launch_bounds__(256, 3) void conv3x3_kernel(
        const unsigned short* __restrict__ featT, const short* __restrict__ Ap,
        const float* __restrict__ bias, float* __restrict__ off27) {
    __shared__ __align__(16) short S[3*66*CST];   // 52.6 KB
    int orig = blockIdx.x;                        // 512 blocks
    int blk = (orig & 7)*64 + (orig >> 3);        // XCD swizzle
    int b = blk >> 6, row = blk & 63;
    int t = threadIdx.x;
    int l = t & 63, wv = t >> 6;

    f32x4 acc[2];
    acc[0] = (f32x4){0.f,0.f,0.f,0.f};
    acc[1] = (f32x4){0.f,0.f,0.f,0.f};
    const unsigned short* fb = featT + (size_t)b*HW*256;

    for (int ch = 0; ch < 2; ch++) {
        for (int i = t; i < 3*66*16; i += 256) {
            int cc = i & 15;
            int rp = i >> 4;
            int r = rp / 66, px_s = rp - r*66;
            int yy = row + r - 1;
            int xx = px_s - 1;
            uint4 v = (uint4){0u,0u,0u,0u};
            if ((unsigned)yy < 64u && (unsigned)xx < 64u)
                v = *(const uint4*)(fb + ((size_t)(yy*64 + xx))*256 + ch*128 + cc*8);
            *(uint4*)(&S[(r*66 + px_s)*CST + cc*8]) = v;
        }
        __syncthreads();
        #pragma unroll
        for (int k = 0; k < 9; k++) {
            int ky = k/3, kx = k%3;
            const short* srow = S + (ky*66 + wv*16 + (l & 15) + kx)*CST + (l >> 4)*8;
            #pragma unroll
            for (int csl = 0; csl < 4; csl++) {
                f16x8 bfrag = *(const f16x8*)(srow + csl*32);
                int cs = ch*4 + csl;
                const short* ap = Ap + ((size_t)((k*2)*8 + cs)*64 + l)*8;
                f16x8 a0 = *(const f16x8*)ap;
                f16x8 a1 = *(const f16x8*)(ap + 8*64*8);
                acc[0] = __builtin_amdgcn_mfma_f32_16x16x32_f16(a0, bfrag, acc[0], 0, 0, 0);
                acc[1] = __builtin_amdgcn_mfma_f32_16x16x32_f16(a1, bfrag, acc[1], 0, 0, 0);
            }
        }
        __syncthreads();
    }
    #pragma unroll
    for (int mt = 0; mt < 2; mt++)
        #pragma unroll
        for (int r = 0; r < 4; r++) {
            int oc = mt*16 + (l >> 4)*4 + r;
            if (oc < 27)
                off27[((size_t)(b*27 + oc))*HW + row*64 + wv*16 + (l & 15)]
                    = acc[mt][r] + bias[oc];
        }
}

// K1b: pack dcn_w into MFMA fragment order, fp16 (A operand).
__global__ void wpack_kernel(const float* __restrict__ w, short* __restrict__ Wp) {
    int idx = blockIdx.x*256 + threadIdx.x;   // 73728
    if (idx >= 9*8*16*64) return;
    int l  = idx & 63;
    int ot = (idx >> 6) & 15;
    int cs = (idx >> 10) & 7;
    int k  = idx >> 13;
    int oc = ot*16 + (l & 15);
    int c0 = cs*32 + (l >> 4)*8;
    short* dst = Wp + (size_t)idx*8;
    #pragma unroll
    for (int i = 0; i < 8; i++) {
        float v = w[((size_t)(oc*256 + c0 + i)*3 + k/3)*3 + (k % 3)];
        dst[i] = (short)f2h(v);
    }
}

// K1c: pack the four 1x1-conv weights into MFMA A-fragment order (320 oc, bf16).
__global__ void wpack4_kernel(const float* __restrict__ so_w, const float* __restrict__ sc_w,
        const float* __restrict__ uw_w, const float* __restrict__ uo_w,
        short* __restrict__ Wc) {
    int idx = blockIdx.x*256 + threadIdx.x;   // 10240
    if (idx >= 8*20*64) return;
    int l  = idx & 63;
    int ot = (idx >> 6) % 20;
    int cs = idx / (64*20);
    int g  = ot*16 + (l & 15);
    int c0 = cs*32 + (l >> 4)*8;
    const float* src = nullptr; int oc = 0;
    if (g < 136)      { src = so_w; oc = g; }
    else if (g < 187) { src = sc_w; oc = g - 136; }
    else if (g < 238) { src = uw_w; oc = g - 187; }
    else if (g < 289) { src = uo_w; oc = g - 238; }
    short* dst = Wc + (size_t)idx*8;
    #pragma unroll
    for (int i = 0; i < 8; i++)
        dst[i] = src ? (short)f2bf(src[(size_t)oc*256 + c0 + i]) : (short)0;
}

// K2: fused DCNv2 — R13 structure (fp16 lerp + fp16 MFMA, SLD=264, no swizzle)
// + fused GroupNorm partial-stat accumulation in the epilogue.
__global__ __launch_bounds__(512, 4) void dcn_kernel(
        const unsigned short* __restrict__ featT, const float* __restrict__ off27,
        const short* __restrict__ Wp, unsigned short* __restrict__ dcn16,
        float* __restrict__ partial) {
    __shared__ __align__(16) short S[64*SLD];   // 33.8 KB

    int orig = blockIdx.x;                 // 512 blocks
    int blk  = (orig & 7)*64 + (orig >> 3);   // XCD swizzle: xcd == batch
    int b   = blk >> 6;
    int row = blk & 63;

    int t   = threadIdx.x;
    int pxh = t >> 4;          // 0..31
    int cl  = t & 15;          // 8-ch chunk
    int l   = t & 63, wv = t >> 6;   // 8 waves: wv owns oc [wv*32, wv*32+32)

    f32x4 acc[2][4];
    #pragma unroll
    for (int i = 0; i < 2; i++)
        #pragma unroll
        for (int j = 0; j < 4; j++) acc[i][j] = (f32x4){0.f,0.f,0.f,0.f};

    const unsigned short* fT = featT + (size_t)b*HW*256;
    const float* offb = off27 + (size_t)b*27*HW;

    for (int k = 0; k < 9; k++) {
        int kx = k % 3 - 1, ky = k / 3 - 1;
        #pragma unroll
        for (int pp = 0; pp < 2; pp++) {
            int px = pp*32 + pxh;
            int p  = row*64 + px;
            float dyv = offb[(size_t)k*HW + p];
            float dxv = offb[(size_t)(9 + k)*HW + p];
            float mk  = offb[(size_t)(18 + k)*HW + p];
            float m = 1.f/(1.f + expf(-mk));
            Bil bl = bilin((float)(px + kx) + dxv, (float)(row + ky) + dyv);
            __half2 h00 = __float2half2_rn(bl.w00*m);
            __half2 h01 = __float2half2_rn(bl.w01*m);
            __half2 h10 = __float2half2_rn(bl.w10*m);
            __half2 h11 = __float2half2_rn(bl.w11*m);
            #pragma unroll
            for (int cp = 0; cp < 2; cp++) {
                int c0 = cp*128 + cl*8;
                uint4 u00 = *(const uint4*)(fT + (size_t)bl.i00*256 + c0);
                uint4 u01 = *(const uint4*)(fT + (size_t)bl.i01*256 + c0);
                uint4 u10 = *(const uint4*)(fT + (size_t)bl.i10*256 + c0);
                uint4 u11 = *(const uint4*)(fT + (size_t)bl.i11*256 + c0);
                const unsigned* a00 = (const unsigned*)&u00;
                const unsigned* a01 = (const unsigned*)&u01;
                const unsigned* a10 = (const unsigned*)&u10;
                const unsigned* a11 = (const unsigned*)&u11;
                uint4 outp;
                unsigned* op = (unsigned*)&outp;
                #pragma unroll
                for (int q = 0; q < 4; q++) {
                    __half2 r = __hmul2(h11, u2h2(a11[q]));
                    r = __hfma2(h10, u2h2(a10[q]), r);
                    r = __hfma2(h01, u2h2(a01[q]), r);
                    r = __hfma2(h00, u2h2(a00[q]), r);
                    op[q] = h22u(r);
                }
                *(uint4*)(S + px*SLD + c0) = outp;
            }
        }
        __syncthreads();

        const short* wpk = Wp + (size_t)k*8*16*64*8;
        for (int cs = 0; cs < 8; cs++) {
            f16x8 wa[2];
            #pragma unroll
            for (int mt = 0; mt < 2; mt++)
                wa[mt] = *(const f16x8*)(wpk + ((size_t)((cs*16 + (wv*2 + mt))*64 + l))*8);
            f16x8 sb[4];
            #pragma unroll
            for (int pt = 0; pt < 4; pt++)
                sb[pt] = *(const f16x8*)(S + (pt*16 + (l & 15))*SLD
                                            + cs*32 + (l >> 4)*8);
            #pragma unroll
            for (int mt = 0; mt < 2; mt++)
                #pragma unroll
                for (int pt = 0; pt < 4; pt++)
                    acc[mt][pt] = __builtin_amdgcn_mfma_f32_16x16x32_f16(
                        wa[mt], sb[pt], acc[mt][pt], 0, 0, 0);
        }
        __syncthreads();
    }

    // store + fused GN partial stats
    float sg[2] = {0.f, 0.f}, sg2[2] = {0.f, 0.f};
    #pragma unroll
    for (int mt = 0; mt < 2; mt++)
        #pragma unroll
        for (int pt = 0; pt < 4; pt++)
            #pragma unroll
            for (int r = 0; r < 4; r++) {
                int oc = wv*32 + mt*16 + (l >> 4)*4 + r;
                int px = pt*16 + (l & 15);
                float v = acc[mt][pt][r];
                sg[mt] += v; sg2[mt] += v*v;
                dcn16[((size_t)(b*256 + oc))*HW + row*64 + px] = f2bf(v);
            }
    // reduce within 32-lane halves (half <-> group sub-block)
    #pragma unroll
    for (int mt = 0; mt < 2; mt++) {
        float a = sg[mt], c = sg2[mt];
        #pragma unroll
        for (int off = 16; off >= 1; off >>= 1) {
            a += __shfl_xor(a, off, 64);
            c += __shfl_xor(c, off, 64);
        }
        if ((l & 31) == 0) {
            int g = wv*4 + mt*2 + (l >> 5);
            atomicAdd(&partial[((size_t)b*32 + g)*2],     a);
            atomicAdd(&partial[((size_t)b*32 + g)*2 + 1], c);
        }
    }
}

// K5: fused GN-apply + residual (-> out_feat) + 1x1 convs + offset blend.
// 1024 blocks x 32 px, 512 thr / 8 waves, 17 KB LDS -> 4 blocks/CU.
__global__ __launch_bounds__(512, 4) void fused_tail_kernel(
        const float* __restrict__ feat, const unsigned short* __restrict__ dcn16,
        const float* __restrict__ partial, const float* __restrict__ gn_g,
        const float* __restrict__ gn_b, const short* __restrict__ Wc,
        const float* __restrict__ so_b, const float* __restrict__ sc_b,
        const float* __restrict__ uw_b, const float* __restrict__ uo_b,
        const float* __restrict__ prev_off,
        float* __restrict__ out_feat, float* __restrict__ SO,
        float* __restrict__ UC) {
    __shared__ __align__(16) short S[32*SLDF];  // 17 KB; overlaid by U after GEMM
    __shared__ float gstat[32][2];
    float* U = (float*)S;                       // [102][32] floats = 13 KB

    int orig = blockIdx.x;                      // 1024 blocks
    int swz = (orig & 7)*128 + (orig >> 3);     // XCD swizzle
    int b = swz >> 7;
    int half = swz & 127;
    int row = half >> 1, px0 = (half & 1)*32;
    int t = threadIdx.x;

    if (t < 32) {
        float s  = partial[(size_t)(b*32 + t)*2];
        float s2 = partial[(size_t)(b*32 + t)*2 + 1];
        float inv = 1.f/(8.f*HW);
        float mu = s*inv;
        float var = s2*inv - mu*mu;
        gstat[t][0] = mu;
        gstat[t][1] = rsqrtf(var + 1e-5f);
    }
    __syncthreads();

    int x = t & 31, cq = t >> 5;                // 16 c-groups of 16 channels
    int l = t & 63, wv = t >> 6;
    const float* fb = feat + (size_t)b*CC*HW + row*64 + px0;
    const unsigned short* db = dcn16 + (size_t)b*CC*HW + row*64 + px0;
    float* ob = out_feat + (size_t)b*CC*HW + row*64 + px0;
    #pragma unroll
    for (int j = 0; j < 4; j++) {
        int c0 = cq*16 + j*4;
        float fv[4];
        #pragma unroll
        for (int q = 0; q < 4; q++) {
            int c = c0 + q;
            float mu = gstat[c >> 3][0], rstd = gstat[c >> 3][1];
            float v = (bf2f(db[(size_t)c*HW + x]) - mu)*rstd*gn_g[c] + gn_b[c];
            fv[q] = fb[(size_t)c*HW + x] + fmaxf(v, 0.f);
            ob[(size_t)c*HW + x] = fv[q];
        }
        uint2 pk;
        pk.x = cvt_pk_bf16(fv[0], fv[1]);
        pk.y = cvt_pk_bf16(fv[2], fv[3]);
        *(uint2*)(S + x*SLDF + c0) = pk;
    }
    __syncthreads();

    f32x4 acc[3][2];
    #pragma unroll
    for (int j = 0; j < 3; j++)
        #pragma unroll
        for (int pt = 0; pt < 2; pt++) acc[j][pt] = (f32x4){0.f,0.f,0.f,0.f};

    for (int cs = 0; cs < 8; cs++) {
        bf16x8 bg[2];
        #pragma unroll
        for (int pt = 0; pt < 2; pt++)
            bg[pt] = *(const bf16x8*)(S + (pt*16 + (l & 15))*SLDF
                                        + cs*32 + (l >> 4)*8);
        #pragma unroll
        for (int j = 0; j < 3; j++) {
            int tile = wv + j*8;
            if (tile < 20) {
                bf16x8 a = *(const bf16x8*)(Wc + ((size_t)(cs*20 + tile)*64 + l)*8);
                #pragma unroll
                for (int pt = 0; pt < 2; pt++)
                    acc[j][pt] = __builtin_amdgcn_mfma_f32_16x16x32_bf16(
                        a, bg[pt], acc[j][pt], 0, 0, 0);
            }
        }
    }
    __syncthreads();   // S dead; U live

    #pragma unroll
    for (int j = 0; j < 3; j++) {
        int tile = wv + j*8;
        if (tile < 20) {
            #pragma unroll
            for (int pt = 0; pt < 2; pt++) {
                int px = pt*16 + (l & 15);
                int p = row*64 + px0 + px;
                #pragma unroll
                for (int r = 0; r < 4; r++) {
                    int oc = tile*16 + (l >> 4)*4 + r;
                    float v = acc[j][pt][r];
                    if (oc < 136) {
                        SO[(((size_t)(b*JJ + (oc >> 3))*HW) + p)*8 + (oc & 7)] = v + so_b[oc];
                    } else if (oc < 187) {
                        int o2 = oc - 136;
                        int jj = o2/3, d = o2 - jj*3;
                        UC[(((size_t)(b*JJ + jj)*HW) + p)*8 + 3 + d] = v + sc_b[o2];
                    } else if (oc < 238) {
                        U[(oc-187)*32 + px] = v + uw_b[oc-187];
                    } else if (oc < 289) {
                        U[(51 + oc-238)*32 + px] = v + uo_b[oc-238];
                    }
                }
            }
        }
    }
    __syncthreads();

    const float* pb = prev_off + (size_t)b*51*HW + row*64 + px0;
    for (int i = t; i < 51*32; i += 512) {
        int dful = i >> 5, px = i & 31;
        int jj = dful/3, d = dful - jj*3;
        int p = row*64 + px0 + px;
        float owv = 1.f/(1.f + expf(-U[dful*32 + px]));
        float blend = (1.f - owv)*pb[(size_t)dful*HW + px] + owv*U[(51 + dful)*32 + px];
        UC[(((size_t)(b*JJ + jj)*HW) + p)*8 + d] = blend;
    }
}

// K7: fused sampling + softmax-weighted sum -> new_off (output 1).
__global__ __launch_bounds__(256) void final_kernel(
        const float* __restrict__ UC, const float* __restrict__ SO,
        float* __restrict__ out_off) {
    int orig = blockIdx.x;                   // 0..2175
    int wg = (orig & 7)*272 + (orig >> 3);   // 272 = 17*16 per batch
    int b = wg / 272;
    int rem = wg - b*272;
    int j = rem >> 4;
    int p = (rem & 15)*256 + threadIdx.x;
    int y = p >> 6, x = p & 63;
    const float* ucb = UC + (size_t)(b*JJ + j)*HW*8;
    const float* sob = SO + (size_t)(b*JJ + j)*HW*8;

    float4 own = *(const float4*)(ucb + (size_t)p*8);
    float offx = own.x, offy = own.y;
    F8 sod = ld8(sob + (size_t)p*8);
    const float* sodp = (const float*)&sod;

    Bil bl = bilin((float)x + offx, (float)y + offy);
    float s8[8];
    gsample8(sob, bl, s8);

    float sall[8][2];
    #pragma unroll
    for (int h = 0; h < 4; h++) {
        sall[h][0]   = s8[2*h]   + offx;
        sall[h][1]   = s8[2*h+1] + offy;
        sall[4+h][0] = sodp[2*h];
        sall[4+h][1] = sodp[2*h+1];
    }

    float sv[8][3], lg[8][3];
    #pragma unroll
    for (int n = 0; n < 8; n++) {
        Bil b2 = bilin((float)x + sall[n][0], (float)y + sall[n][1]);
        float v8[8];
        gsample8(ucb, b2, v8);
        #pragma unroll
        for (int d = 0; d < 3; d++) {
            sv[n][d] = v8[d];
            lg[n][d] = v8[3 + d];
        }
        sv[n][0] += sall[n][0];
        sv[n][1] += sall[n][1];
    }
    #pragma unroll
    for (int d = 0; d < 3; d++) {
        float m = lg[0][d];
        #pragma unroll
        for (int n = 1; n < 8; n++) m = fmaxf(m, lg[n][d]);
        float den = 0.f, num = 0.f;
        #pragma unroll
        for (int n = 0; n < 8; n++) {
            float e = expf(lg[n][d]-m);
            den += e; num += e*sv[n][d];
        }
        out_off[((size_t)b*51 + j*3 + d)*HW + p] = num/den;
    }
}

extern "C" void kernel_launch(void* const* d_in, const int* in_sizes, int n_in,
                              void* d_out, int out_size, void* d_ws, size_t ws_size,
                              hipStream_t stream) {
    const float* feat       = (const float*)d_in[0];
    const float* prev_off   = (const float*)d_in[1];
    const float* dcn_off_w  = (const float*)d_in[2];
    const float* dcn_off_b  = (const float*)d_in[3];
    const float* dcn_w      = (const float*)d_in[4];
    const float* gn_g       = (const float*)d_in[5];
    const float* gn_b       = (const float*)d_in[6];
    const float* so_w       = (const float*)d_in[7];
    const float* so_b       = (const float*)d_in[8];
    const float* sc_w       = (const float*)d_in[9];
    const float* sc_b       = (const float*)d_in[10];
    const float* uw_w       = (const float*)d_in[11];
    const float* uw_b       = (const float*)d_in[12];
    const float* uo_w       = (const float*)d_in[13];
    const float* uo_b       = (const float*)d_in[14];

    float* ws = (float*)d_ws;
    float* off27     = ws;                       // 884736 floats
    float* Wt        = off27 + 884736;           // pack region
    short* Wp        = (short*)Wt;               // 589824 shorts (dcn weights, fp16)
    short* Ap        = Wp + 589824;              // 73728 shorts (conv3x3 weights, fp16)
    short* Wc        = Ap + 73728;               // 81920 shorts (1x1 weights, bf16)
    float* dcnreg    = Wt + 589824;              // 8388608-float region
    unsigned short* dcn16 = (unsigned short*)dcnreg;   // 8.4M ushorts (bf16)
    float* partial   = dcnreg + 8388608;         // 512 floats (atomically accumulated)
    float* SO        = partial + 2048;           // 4456448 (8*17*4096*8)
    float* UC        = SO + 4456448;             // 4456448

    // featT aliases SO (dead after dcn_kernel; SO written by fused_tail)
    unsigned short* featT = (unsigned short*)SO;

    float* out_feat = (float*)d_out;             // 8388608
    float* out_off  = out_feat + 8388608;        // 1671168

    // zero GN partial accumulators (graph-capture-legal async memset)
    hipMemsetAsync(partial, 0, 512*sizeof(float), stream);

    // K0: NCHW f32 -> NHWC fp16 transpose
    nhwc_kernel<<<dim3(BB*64), dim3(256), 0, stream>>>(feat, featT);
    // packs
    cpack_kernel<<<dim3(36), dim3(256), 0, stream>>>(dcn_off_w, Ap);
    wpack_kernel<<<dim3(288), dim3(256), 0, stream>>>(dcn_w, Wp);
    wpack4_kernel<<<dim3(40), dim3(256), 0, stream>>>(so_w, sc_w, uw_w, uo_w, Wc);
    // K1: offset conv (3x3, MFMA fp16)
    conv3x3_kernel<<<dim3(BB*64), dim3(256), 0, stream>>>(featT, Ap, dcn_off_b, off27);
    // K2: DCN (R13 structure, fp16; fused GN partial stats)
    dcn_kernel<<<dim3(BB*64), dim3(512), 0, stream>>>(featT, off27, Wp, dcn16, partial);
    // K5: fused GN + residual + 1x1 convs + offset blend (1024 x 32px blocks)
    fused_tail_kernel<<<dim3(1024), dim3(512), 0, stream>>>(feat, dcn16, partial,
        gn_g, gn_b, Wc, so_b, sc_b, uw_b, uo_b, prev_off,
        out_feat, SO, UC);
    // K7: fused double grid-sample + softmax reduction (packed gathers)
    final_kernel<<<dim3(2176), dim3(256), 0, stream>>>(UC, SO, out_off);
}

// Round 16
// 179.985 us; speedup vs baseline: 1.0615x; 1.0615x over previous
//
#include <hip/hip_runtime.h>
#include <hip/hip_bf16.h>
#include <hip/hip_fp16.h>
#include <math.h>

// Problem constants: B=8, C=256, H=W=64, J=17, Hd=4, dim=3
#define HH 64
#define WW 64
#define HW 4096
#define CC 256
#define BB 8
#define JJ 17

typedef __attribute__((ext_vector_type(8))) short bf16x8;
typedef __attribute__((ext_vector_type(8))) _Float16 f16x8;
typedef __attribute__((ext_vector_type(4))) float f32x4;

#define SLD 264    // dcn LDS row stride (shorts): additive spread, R13-proven
#define SLDF 266   // fused_tail stride (shorts)
#define CST 136    // conv3x3 strip c-stride in shorts
#define TLD 266    // transpose LDS stride in shorts

struct Bil { int i00,i01,i10,i11; float w00,w01,w10,w11; };

__device__ inline Bil bilin(float sx, float sy) {
    float x0f = floorf(sx), y0f = floorf(sy);
    float wx1 = sx - x0f, wy1 = sy - y0f;
    float wx0 = 1.f - wx1, wy0 = 1.f - wy1;
    int x0 = (int)x0f, y0 = (int)y0f;
    int x1 = x0 + 1, y1 = y0 + 1;
    bool vx0 = (unsigned)x0 < (unsigned)WW;
    bool vx1 = (unsigned)x1 < (unsigned)WW;
    bool vy0 = (unsigned)y0 < (unsigned)HH;
    bool vy1 = (unsigned)y1 < (unsigned)HH;
    int x0c = min(max(x0,0),WW-1), x1c = min(max(x1,0),WW-1);
    int y0c = min(max(y0,0),HH-1), y1c = min(max(y1,0),HH-1);
    Bil b;
    b.i00 = y0c*WW + x0c; b.i01 = y0c*WW + x1c;
    b.i10 = y1c*WW + x0c; b.i11 = y1c*WW + x1c;
    b.w00 = wx0*wy0*((vx0&&vy0)?1.f:0.f);
    b.w01 = wx1*wy0*((vx1&&vy0)?1.f:0.f);
    b.w10 = wx0*wy1*((vx0&&vy1)?1.f:0.f);
    b.w11 = wx1*wy1*((vx1&&vy1)?1.f:0.f);
    return b;
}

__device__ inline unsigned short f2bf(float f) {
    unsigned u = __float_as_uint(f);
    unsigned r = (u + 0x7fffu + ((u >> 16) & 1u)) >> 16;
    return (unsigned short)r;
}
__device__ inline unsigned short f2h(float f) {
    return __half_as_ushort(__float2half(f));
}
__device__ inline unsigned cvt_pk_bf16(float lo, float hi) {
    unsigned r;
    asm("v_cvt_pk_bf16_f32 %0, %1, %2" : "=v"(r) : "v"(lo), "v"(hi));
    return r;
}
__device__ inline float bflo(unsigned u) { return __uint_as_float(u << 16); }
__device__ inline float bfhi(unsigned u) { return __uint_as_float(u & 0xFFFF0000u); }
__device__ inline float bf2f(unsigned short us) { return __uint_as_float(((unsigned)us) << 16); }
__device__ inline __half2 u2h2(unsigned u) { union { unsigned u; __half2 h; } c; c.u = u; return c.h; }
__device__ inline unsigned h22u(__half2 h) { union { unsigned u; __half2 h; } c; c.h = h; return c.u; }

struct F8 { float4 a, b; };
__device__ inline F8 ld8(const float* p) {
    F8 r; r.a = *(const float4*)p; r.b = *(const float4*)(p + 4); return r;
}
__device__ inline void gsample8(const float* base, const Bil& bl, float out[8]) {
    F8 v00 = ld8(base + (size_t)bl.i00*8);
    F8 v01 = ld8(base + (size_t)bl.i01*8);
    F8 v10 = ld8(base + (size_t)bl.i10*8);
    F8 v11 = ld8(base + (size_t)bl.i11*8);
    const float* p00 = (const float*)&v00;
    const float* p01 = (const float*)&v01;
    const float* p10 = (const float*)&v10;
    const float* p11 = (const float*)&v11;
    #pragma unroll
    for (int i = 0; i < 8; i++)
        out[i] = bl.w00*p00[i] + bl.w01*p01[i] + bl.w10*p10[i] + bl.w11*p11[i];
}

// K0: transpose feat (NCHW f32) -> featT (N,px,c) fp16.
__global__ __launch_bounds__(256) void nhwc_kernel(
        const float* __restrict__ feat, unsigned short* __restrict__ featT) {
    __shared__ unsigned short T[64*TLD];   // 34 KB
    int b = blockIdx.x >> 6, p0 = (blockIdx.x & 63)*64;
    int t = threadIdx.x;
    int x = t & 63, c4 = t >> 6;
    const float* fb = feat + (size_t)b*CC*HW + p0;
    #pragma unroll 4
    for (int cp = 0; cp < 256; cp += 4) {
        int c = cp + c4;
        T[x*TLD + c] = f2h(fb[(size_t)c*HW + x]);
    }
    __syncthreads();
    int xq = t >> 5, cl = t & 31;
    unsigned short* dst = featT + ((size_t)b*HW + p0)*256;
    #pragma unroll
    for (int w = 0; w < 8; w++) {
        int xr = w*8 + xq;
        *(uint4*)(dst + (size_t)xr*256 + cl*8) = *(const uint4*)(T + xr*TLD + cl*8);
    }
}

// K1a: pack dcn_off_w into MFMA A-fragment order, fp16.
__global__ void cpack_kernel(const float* __restrict__ w, short* __restrict__ Ap) {
    int idx = blockIdx.x*256 + threadIdx.x;   // 9216
    if (idx >= 9*2*8*64) return;
    int l  = idx & 63;
    int cs = (idx >> 6) & 7;
    int mt = (idx >> 9) & 1;
    int k  = idx >> 10;
    int oc = mt*16 + (l & 15);
    int c0 = cs*32 + (l >> 4)*8;
    short* dst = Ap + (size_t)idx*8;
    #pragma unroll
    for (int i = 0; i < 8; i++) {
        float v = (oc < 27) ? w[((size_t)(oc*256 + c0 + i)*3 + k/3)*3 + (k % 3)] : 0.f;
        dst[i] = (short)f2h(v);
    }
}

// K1: 3x3 conv featT (fp16) -> off27 via MFMA on a 3-row strip.
__global__ __launch_bounds__(256, 3) void conv3x3_kernel(
        const unsigned short* __restrict__ featT, const short* __restrict__ Ap,
        const float* __restrict__ bias, float* __restrict__ off27) {
    __shared__ __align__(16) short S[3*66*CST];   // 52.6 KB
    int orig = blockIdx.x;                        // 512 blocks
    int blk = (orig & 7)*64 + (orig >> 3);        // XCD swizzle
    int b = blk >> 6, row = blk & 63;
    int t = threadIdx.x;
    int l = t & 63, wv = t >> 6;

    f32x4 acc[2];
    acc[0] = (f32x4){0.f,0.f,0.f,0.f};
    acc[1] = (f32x4){0.f,0.f,0.f,0.f};
    const unsigned short* fb = featT + (size_t)b*HW*256;

    for (int ch = 0; ch < 2; ch++) {
        for (int i = t; i < 3*66*16; i += 256) {
            int cc = i & 15;
            int rp = i >> 4;
            int r = rp / 66, px_s = rp - r*66;
            int yy = row + r - 1;
            int xx = px_s - 1;
            uint4 v = (uint4){0u,0u,0u,0u};
            if ((unsigned)yy < 64u && (unsigned)xx < 64u)
                v = *(const uint4*)(fb + ((size_t)(yy*64 + xx))*256 + ch*128 + cc*8);
            *(uint4*)(&S[(r*66 + px_s)*CST + cc*8]) = v;
        }
        __syncthreads();
        #pragma unroll
        for (int k = 0; k < 9; k++) {
            int ky = k/3, kx = k%3;
            const short* srow = S + (ky*66 + wv*16 + (l & 15) + kx)*CST + (l >> 4)*8;
            #pragma unroll
            for (int csl = 0; csl < 4; csl++) {
                f16x8 bfrag = *(const f16x8*)(srow + csl*32);
                int cs = ch*4 + csl;
                const short* ap = Ap + ((size_t)((k*2)*8 + cs)*64 + l)*8;
                f16x8 a0 = *(const f16x8*)ap;
                f16x8 a1 = *(const f16x8*)(ap + 8*64*8);
                acc[0] = __builtin_amdgcn_mfma_f32_16x16x32_f16(a0, bfrag, acc[0], 0, 0, 0);
                acc[1] = __builtin_amdgcn_mfma_f32_16x16x32_f16(a1, bfrag, acc[1], 0, 0, 0);
            }
        }
        __syncthreads();
    }
    #pragma unroll
    for (int mt = 0; mt < 2; mt++)
        #pragma unroll
        for (int r = 0; r < 4; r++) {
            int oc = mt*16 + (l >> 4)*4 + r;
            if (oc < 27)
                off27[((size_t)(b*27 + oc))*HW + row*64 + wv*16 + (l & 15)]
                    = acc[mt][r] + bias[oc];
        }
}

// K1b: pack dcn_w into MFMA fragment order, fp16 (A operand).
__global__ void wpack_kernel(const float* __restrict__ w, short* __restrict__ Wp) {
    int idx = blockIdx.x*256 + threadIdx.x;   // 73728
    if (idx >= 9*8*16*64) return;
    int l  = idx & 63;
    int ot = (idx >> 6) & 15;
    int cs = (idx >> 10) & 7;
    int k  = idx >> 13;
    int oc = ot*16 + (l & 15);
    int c0 = cs*32 + (l >> 4)*8;
    short* dst = Wp + (size_t)idx*8;
    #pragma unroll
    for (int i = 0; i < 8; i++) {
        float v = w[((size_t)(oc*256 + c0 + i)*3 + k/3)*3 + (k % 3)];
        dst[i] = (short)f2h(v);
    }
}

// K1c: pack the four 1x1-conv weights into MFMA A-fragment order (320 oc, bf16).
__global__ void wpack4_kernel(const float* __restrict__ so_w, const float* __restrict__ sc_w,
        const float* __restrict__ uw_w, const float* __restrict__ uo_w,
        short* __restrict__ Wc) {
    int idx = blockIdx.x*256 + threadIdx.x;   // 10240
    if (idx >= 8*20*64) return;
    int l  = idx & 63;
    int ot = (idx >> 6) % 20;
    int cs = idx / (64*20);
    int g  = ot*16 + (l & 15);
    int c0 = cs*32 + (l >> 4)*8;
    const float* src = nullptr; int oc = 0;
    if (g < 136)      { src = so_w; oc = g; }
    else if (g < 187) { src = sc_w; oc = g - 136; }
    else if (g < 238) { src = uw_w; oc = g - 187; }
    else if (g < 289) { src = uo_w; oc = g - 238; }
    short* dst = Wc + (size_t)idx*8;
    #pragma unroll
    for (int i = 0; i < 8; i++)
        dst[i] = src ? (short)f2bf(src[(size_t)oc*256 + c0 + i]) : (short)0;
}

// K2: fused DCNv2 — R13 exact: fp16 lerp + fp16 MFMA, SLD=264, plain epilogue.
__global__ __launch_bounds__(512, 4) void dcn_kernel(
        const unsigned short* __restrict__ featT, const float* __restrict__ off27,
        const short* __restrict__ Wp, unsigned short* __restrict__ dcn16) {
    __shared__ __align__(16) short S[64*SLD];   // 33.8 KB

    int orig = blockIdx.x;                 // 512 blocks
    int blk  = (orig & 7)*64 + (orig >> 3);   // XCD swizzle: xcd == batch
    int b   = blk >> 6;
    int row = blk & 63;

    int t   = threadIdx.x;
    int pxh = t >> 4;          // 0..31
    int cl  = t & 15;          // 8-ch chunk
    int l   = t & 63, wv = t >> 6;   // 8 waves: wv owns oc [wv*32, wv*32+32)

    f32x4 acc[2][4];
    #pragma unroll
    for (int i = 0; i < 2; i++)
        #pragma unroll
        for (int j = 0; j < 4; j++) acc[i][j] = (f32x4){0.f,0.f,0.f,0.f};

    const unsigned short* fT = featT + (size_t)b*HW*256;
    const float* offb = off27 + (size_t)b*27*HW;

    for (int k = 0; k < 9; k++) {
        int kx = k % 3 - 1, ky = k / 3 - 1;
        #pragma unroll
        for (int pp = 0; pp < 2; pp++) {
            int px = pp*32 + pxh;
            int p  = row*64 + px;
            float dyv = offb[(size_t)k*HW + p];
            float dxv = offb[(size_t)(9 + k)*HW + p];
            float mk  = offb[(size_t)(18 + k)*HW + p];
            float m = 1.f/(1.f + expf(-mk));
            Bil bl = bilin((float)(px + kx) + dxv, (float)(row + ky) + dyv);
            __half2 h00 = __float2half2_rn(bl.w00*m);
            __half2 h01 = __float2half2_rn(bl.w01*m);
            __half2 h10 = __float2half2_rn(bl.w10*m);
            __half2 h11 = __float2half2_rn(bl.w11*m);
            #pragma unroll
            for (int cp = 0; cp < 2; cp++) {
                int c0 = cp*128 + cl*8;
                uint4 u00 = *(const uint4*)(fT + (size_t)bl.i00*256 + c0);
                uint4 u01 = *(const uint4*)(fT + (size_t)bl.i01*256 + c0);
                uint4 u10 = *(const uint4*)(fT + (size_t)bl.i10*256 + c0);
                uint4 u11 = *(const uint4*)(fT + (size_t)bl.i11*256 + c0);
                const unsigned* a00 = (const unsigned*)&u00;
                const unsigned* a01 = (const unsigned*)&u01;
                const unsigned* a10 = (const unsigned*)&u10;
                const unsigned* a11 = (const unsigned*)&u11;
                uint4 outp;
                unsigned* op = (unsigned*)&outp;
                #pragma unroll
                for (int q = 0; q < 4; q++) {
                    __half2 r = __hmul2(h11, u2h2(a11[q]));
                    r = __hfma2(h10, u2h2(a10[q]), r);
                    r = __hfma2(h01, u2h2(a01[q]), r);
                    r = __hfma2(h00, u2h2(a00[q]), r);
                    op[q] = h22u(r);
                }
                *(uint4*)(S + px*SLD + c0) = outp;
            }
        }
        __syncthreads();

        const short* wpk = Wp + (size_t)k*8*16*64*8;
        for (int cs = 0; cs < 8; cs++) {
            f16x8 wa[2];
            #pragma unroll
            for (int mt = 0; mt < 2; mt++)
                wa[mt] = *(const f16x8*)(wpk + ((size_t)((cs*16 + (wv*2 + mt))*64 + l))*8);
            f16x8 sb[4];
            #pragma unroll
            for (int pt = 0; pt < 4; pt++)
                sb[pt] = *(const f16x8*)(S + (pt*16 + (l & 15))*SLD
                                            + cs*32 + (l >> 4)*8);
            #pragma unroll
            for (int mt = 0; mt < 2; mt++)
                #pragma unroll
                for (int pt = 0; pt < 4; pt++)
                    acc[mt][pt] = __builtin_amdgcn_mfma_f32_16x16x32_f16(
                        wa[mt], sb[pt], acc[mt][pt], 0, 0, 0);
        }
        __syncthreads();
    }

    #pragma unroll
    for (int mt = 0; mt < 2; mt++)
        #pragma unroll
        for (int pt = 0; pt < 4; pt++)
            #pragma unroll
            for (int r = 0; r < 4; r++) {
                int oc = wv*32 + mt*16 + (l >> 4)*4 + r;
                int px = pt*16 + (l & 15);
                dcn16[((size_t)(b*256 + oc))*HW + row*64 + px] = f2bf(acc[mt][pt][r]);
            }
}

// K3: GroupNorm partial sums from bf16 dcn: 1024 blocks, 2 channels each.
__global__ __launch_bounds__(256) void gn_partial_kernel(
        const unsigned short* __restrict__ dcn16, float* __restrict__ partial) {
    int blk = blockIdx.x;
    const uint4* base = (const uint4*)(dcn16 + (size_t)blk*2*HW);
    float s = 0.f, s2 = 0.f;
    #pragma unroll
    for (int j = 0; j < 4; j++) {
        uint4 v = base[threadIdx.x + j*256];
        const unsigned* u = (const unsigned*)&v;
        #pragma unroll
        for (int q = 0; q < 4; q++) {
            float lo = bflo(u[q]), hi = bfhi(u[q]);
            s += lo + hi; s2 += lo*lo + hi*hi;
        }
    }
    __shared__ float rs[256], rs2[256];
    rs[threadIdx.x] = s; rs2[threadIdx.x] = s2; __syncthreads();
    for (int o = 128; o > 0; o >>= 1) {
        if (threadIdx.x < o) { rs[threadIdx.x] += rs[threadIdx.x+o]; rs2[threadIdx.x] += rs2[threadIdx.x+o]; }
        __syncthreads();
    }
    if (threadIdx.x == 0) { partial[blk*2] = rs[0]; partial[blk*2+1] = rs2[0]; }
}

// K5: fused GN-apply + residual (-> out_feat) + 1x1 convs + offset blend.
// 1024 blocks x 32 px, 512 thr / 8 waves, 17 KB LDS -> 4 blocks/CU.
__global__ __launch_bounds__(512, 4) void fused_tail_kernel(
        const float* __restrict__ feat, const unsigned short* __restrict__ dcn16,
        const float* __restrict__ partial, const float* __restrict__ gn_g,
        const float* __restrict__ gn_b, const short* __restrict__ Wc,
        const float* __restrict__ so_b, const float* __restrict__ sc_b,
        const float* __restrict__ uw_b, const float* __restrict__ uo_b,
        const float* __restrict__ prev_off,
        float* __restrict__ out_feat, float* __restrict__ SO,
        float* __restrict__ UC) {
    __shared__ __align__(16) short S[32*SLDF];  // 17 KB; overlaid by U after GEMM
    __shared__ float gstat[32][2];
    float* U = (float*)S;                       // [102][32] floats = 13 KB

    int orig = blockIdx.x;                      // 1024 blocks
    int swz = (orig & 7)*128 + (orig >> 3);     // XCD swizzle
    int b = swz >> 7;
    int half = swz & 127;
    int row = half >> 1, px0 = (half & 1)*32;
    int t = threadIdx.x;

    if (t < 32) {
        const float* pp = partial + (size_t)(b*32 + t)*8;
        float s  = pp[0] + pp[2] + pp[4] + pp[6];
        float s2 = pp[1] + pp[3] + pp[5] + pp[7];
        float inv = 1.f/(8.f*HW);
        float mu = s*inv;
        float var = s2*inv - mu*mu;
        gstat[t][0] = mu;
        gstat[t][1] = rsqrtf(var + 1e-5f);
    }
    __syncthreads();

    int x = t & 31, cq = t >> 5;                // 16 c-groups of 16 channels
    int l = t & 63, wv = t >> 6;
    const float* fb = feat + (size_t)b*CC*HW + row*64 + px0;
    const unsigned short* db = dcn16 + (size_t)b*CC*HW + row*64 + px0;
    float* ob = out_feat + (size_t)b*CC*HW + row*64 + px0;
    #pragma unroll
    for (int j = 0; j < 4; j++) {
        int c0 = cq*16 + j*4;
        float fv[4];
        #pragma unroll
        for (int q = 0; q < 4; q++) {
            int c = c0 + q;
            float mu = gstat[c >> 3][0], rstd = gstat[c >> 3][1];
            float v = (bf2f(db[(size_t)c*HW + x]) - mu)*rstd*gn_g[c] + gn_b[c];
            fv[q] = fb[(size_t)c*HW + x] + fmaxf(v, 0.f);
            ob[(size_t)c*HW + x] = fv[q];
        }
        uint2 pk;
        pk.x = cvt_pk_bf16(fv[0], fv[1]);
        pk.y = cvt_pk_bf16(fv[2], fv[3]);
        *(uint2*)(S + x*SLDF + c0) = pk;
    }
    __syncthreads();

    f32x4 acc[3][2];
    #pragma unroll
    for (int j = 0; j < 3; j++)
        #pragma unroll
        for (int pt = 0; pt < 2; pt++) acc[j][pt] = (f32x4){0.f,0.f,0.f,0.f};

    for (int cs = 0; cs < 8; cs++) {
        bf16x8 bg[2];
        #pragma unroll
        for (int pt = 0; pt < 2; pt++)
            bg[pt] = *(const bf16x8*)(S + (pt*16 + (l & 15))*SLDF
                                        + cs*32 + (l >> 4)*8);
        #pragma unroll
        for (int j = 0; j < 3; j++) {
            int tile = wv + j*8;
            if (tile < 20) {
                bf16x8 a = *(const bf16x8*)(Wc + ((size_t)(cs*20 + tile)*64 + l)*8);
                #pragma unroll
                for (int pt = 0; pt < 2; pt++)
                    acc[j][pt] = __builtin_amdgcn_mfma_f32_16x16x32_bf16(
                        a, bg[pt], acc[j][pt], 0, 0, 0);
            }
        }
    }
    __syncthreads();   // S dead; U live

    #pragma unroll
    for (int j = 0; j < 3; j++) {
        int tile = wv + j*8;
        if (tile < 20) {
            #pragma unroll
            for (int pt = 0; pt < 2; pt++) {
                int px = pt*16 + (l & 15);
                int p = row*64 + px0 + px;
                #pragma unroll
                for (int r = 0; r < 4; r++) {
                    int oc = tile*16 + (l >> 4)*4 + r;
                    float v = acc[j][pt][r];
                    if (oc < 136) {
                        SO[(((size_t)(b*JJ + (oc >> 3))*HW) + p)*8 + (oc & 7)] = v + so_b[oc];
                    } else if (oc < 187) {
                        int o2 = oc - 136;
                        int jj = o2/3, d = o2 - jj*3;
                        UC[(((size_t)(b*JJ + jj)*HW) + p)*8 + 3 + d] = v + sc_b[o2];
                    } else if (oc < 238) {
                        U[(oc-187)*32 + px] = v + uw_b[oc-187];
                    } else if (oc < 289) {
                        U[(51 + oc-238)*32 + px] = v + uo_b[oc-238];
                    }
                }
            }
        }
    }
    __syncthreads();

    const float* pb = prev_off + (size_t)b*51*HW + row*64 + px0;
    for (int i = t; i < 51*32; i += 512) {
        int dful = i >> 5, px = i & 31;
        int jj = dful/3, d = dful - jj*3;
        int p = row*64 + px0 + px;
        float owv = 1.f/(1.f + expf(-U[dful*32 + px]));
        float blend = (1.f - owv)*pb[(size_t)dful*HW + px] + owv*U[(51 + dful)*32 + px];
        UC[(((size_t)(b*JJ + jj)*HW) + p)*8 + d] = blend;
    }
}

// K7: fused sampling + softmax-weighted sum -> new_off (output 1).
__global__ __launch_bounds__(256) void final_kernel(
        const float* __restrict__ UC, const float* __restrict__ SO,
        float* __restrict__ out_off) {
    int orig = blockIdx.x;                   // 0..2175
    int wg = (orig & 7)*272 + (orig >> 3);   // 272 = 17*16 per batch
    int b = wg / 272;
    int rem = wg - b*272;
    int j = rem >> 4;
    int p = (rem & 15)*256 + threadIdx.x;
    int y = p >> 6, x = p & 63;
    const float* ucb = UC + (size_t)(b*JJ + j)*HW*8;
    const float* sob = SO + (size_t)(b*JJ + j)*HW*8;

    float4 own = *(const float4*)(ucb + (size_t)p*8);
    float offx = own.x, offy = own.y;
    F8 sod = ld8(sob + (size_t)p*8);
    const float* sodp = (const float*)&sod;

    Bil bl = bilin((float)x + offx, (float)y + offy);
    float s8[8];
    gsample8(sob, bl, s8);

    float sall[8][2];
    #pragma unroll
    for (int h = 0; h < 4; h++) {
        sall[h][0]   = s8[2*h]   + offx;
        sall[h][1]   = s8[2*h+1] + offy;
        sall[4+h][0] = sodp[2*h];
        sall[4+h][1] = sodp[2*h+1];
    }

    float sv[8][3], lg[8][3];
    #pragma unroll
    for (int n = 0; n < 8; n++) {
        Bil b2 = bilin((float)x + sall[n][0], (float)y + sall[n][1]);
        float v8[8];
        gsample8(ucb, b2, v8);
        #pragma unroll
        for (int d = 0; d < 3; d++) {
            sv[n][d] = v8[d];
            lg[n][d] = v8[3 + d];
        }
        sv[n][0] += sall[n][0];
        sv[n][1] += sall[n][1];
    }
    #pragma unroll
    for (int d = 0; d < 3; d++) {
        float m = lg[0][d];
        #pragma unroll
        for (int n = 1; n < 8; n++) m = fmaxf(m, lg[n][d]);
        float den = 0.f, num = 0.f;
        #pragma unroll
        for (int n = 0; n < 8; n++) {
            float e = expf(lg[n][d]-m);
            den += e; num += e*sv[n][d];
        }
        out_off[((size_t)b*51 + j*3 + d)*HW + p] = num/den;
    }
}

extern "C" void kernel_launch(void* const* d_in, const int* in_sizes, int n_in,
                              void* d_out, int out_size, void* d_ws, size_t ws_size,
                              hipStream_t stream) {
    const float* feat       = (const float*)d_in[0];
    const float* prev_off   = (const float*)d_in[1];
    const float* dcn_off_w  = (const float*)d_in[2];
    const float* dcn_off_b  = (const float*)d_in[3];
    const float* dcn_w      = (const float*)d_in[4];
    const float* gn_g       = (const float*)d_in[5];
    const float* gn_b       = (const float*)d_in[6];
    const float* so_w       = (const float*)d_in[7];
    const float* so_b       = (const float*)d_in[8];
    const float* sc_w       = (const float*)d_in[9];
    const float* sc_b       = (const float*)d_in[10];
    const float* uw_w       = (const float*)d_in[11];
    const float* uw_b       = (const float*)d_in[12];
    const float* uo_w       = (const float*)d_in[13];
    const float* uo_b       = (const float*)d_in[14];

    float* ws = (float*)d_ws;
    float* off27     = ws;                       // 884736 floats
    float* Wt        = off27 + 884736;           // pack region
    short* Wp        = (short*)Wt;               // 589824 shorts (dcn weights, fp16)
    short* Ap        = Wp + 589824;              // 73728 shorts (conv3x3 weights, fp16)
    short* Wc        = Ap + 73728;               // 81920 shorts (1x1 weights, bf16)
    float* dcnreg    = Wt + 589824;              // 8388608-float region
    unsigned short* dcn16 = (unsigned short*)dcnreg;   // 8.4M ushorts (bf16)
    float* partial   = dcnreg + 8388608;         // 2048
    float* SO        = partial + 2048;           // 4456448 (8*17*4096*8)
    float* UC        = SO + 4456448;             // 4456448

    // featT aliases SO (dead after dcn_kernel; SO written by fused_tail)
    unsigned short* featT = (unsigned short*)SO;

    float* out_feat = (float*)d_out;             // 8388608
    float* out_off  = out_feat + 8388608;        // 1671168

    // K0: NCHW f32 -> NHWC fp16 transpose
    nhwc_kernel<<<dim3(BB*64), dim3(256), 0, stream>>>(feat, featT);
    // packs
    cpack_kernel<<<dim3(36), dim3(256), 0, stream>>>(dcn_off_w, Ap);
    wpack_kernel<<<dim3(288), dim3(256), 0, stream>>>(dcn_w, Wp);
    wpack4_kernel<<<dim3(40), dim3(256), 0, stream>>>(so_w, sc_w, uw_w, uo_w, Wc);
    // K1: offset conv (3x3, MFMA fp16)
    conv3x3_kernel<<<dim3(BB*64), dim3(256), 0, stream>>>(featT, Ap, dcn_off_b, off27);
    // K2: DCN (R13 exact)
    dcn_kernel<<<dim3(BB*64), dim3(512), 0, stream>>>(featT, off27, Wp, dcn16);
    // K3: GroupNorm partials (bf16 input)
    gn_partial_kernel<<<dim3(1024), dim3(256), 0, stream>>>(dcn16, partial);
    // K5: fused GN + residual + 1x1 convs + offset blend (1024 x 32px blocks)
    fused_tail_kernel<<<dim3(1024), dim3(512), 0, stream>>>(feat, dcn16, partial,
        gn_g, gn_b, Wc, so_b, sc_b, uw_b, uo_b, prev_off,
        out_feat, SO, UC);
    // K7: fused double grid-sample + softmax reduction (packed gathers)
    final_kernel<<<dim3(2176), dim3(256), 0, stream>>>(UC, SO, out_off);
}

// Round 17
// 172.343 us; speedup vs baseline: 1.1086x; 1.0443x over previous
//
#include <hip/hip_runtime.h>
#include <hip/hip_bf16.h>
#include <hip/hip_fp16.h>
#include <math.h>

// Problem constants: B=8, C=256, H=W=64, J=17, Hd=4, dim=3
#define HH 64
#define WW 64
#define HW 4096
#define CC 256
#define BB 8
#define JJ 17

typedef __attribute__((ext_vector_type(8))) short bf16x8;
typedef __attribute__((ext_vector_type(8))) _Float16 f16x8;
typedef __attribute__((ext_vector_type(4))) float f32x4;

#define SLD 264    // dcn LDS row stride (shorts)
#define SLDF 266   // fused_tail stride (shorts)
#define CST 136    // conv strip c-stride in shorts
#define TLD 266    // transpose LDS stride in shorts

struct Bil { int i00,i01,i10,i11; float w00,w01,w10,w11; };

__device__ inline Bil bilin(float sx, float sy) {
    float x0f = floorf(sx), y0f = floorf(sy);
    float wx1 = sx - x0f, wy1 = sy - y0f;
    float wx0 = 1.f - wx1, wy0 = 1.f - wy1;
    int x0 = (int)x0f, y0 = (int)y0f;
    int x1 = x0 + 1, y1 = y0 + 1;
    bool vx0 = (unsigned)x0 < (unsigned)WW;
    bool vx1 = (unsigned)x1 < (unsigned)WW;
    bool vy0 = (unsigned)y0 < (unsigned)HH;
    bool vy1 = (unsigned)y1 < (unsigned)HH;
    int x0c = min(max(x0,0),WW-1), x1c = min(max(x1,0),WW-1);
    int y0c = min(max(y0,0),HH-1), y1c = min(max(y1,0),HH-1);
    Bil b;
    b.i00 = y0c*WW + x0c; b.i01 = y0c*WW + x1c;
    b.i10 = y1c*WW + x0c; b.i11 = y1c*WW + x1c;
    b.w00 = wx0*wy0*((vx0&&vy0)?1.f:0.f);
    b.w01 = wx1*wy0*((vx1&&vy0)?1.f:0.f);
    b.w10 = wx0*wy1*((vx0&&vy1)?1.f:0.f);
    b.w11 = wx1*wy1*((vx1&&vy1)?1.f:0.f);
    return b;
}

__device__ inline unsigned short f2bf(float f) {
    unsigned u = __float_as_uint(f);
    unsigned r = (u + 0x7fffu + ((u >> 16) & 1u)) >> 16;
    return (unsigned short)r;
}
__device__ inline unsigned short f2h(float f) {
    return __half_as_ushort(__float2half(f));
}
__device__ inline unsigned cvt_pk_bf16(float lo, float hi) {
    unsigned r;
    asm("v_cvt_pk_bf16_f32 %0, %1, %2" : "=v"(r) : "v"(lo), "v"(hi));
    return r;
}
__device__ inline float bflo(unsigned u) { return __uint_as_float(u << 16); }
__device__ inline float bfhi(unsigned u) { return __uint_as_float(u & 0xFFFF0000u); }
__device__ inline float bf2f(unsigned short us) { return __uint_as_float(((unsigned)us) << 16); }
__device__ inline __half2 u2h2(unsigned u) { union { unsigned u; __half2 h; } c; c.u = u; return c.h; }
__device__ inline unsigned h22u(__half2 h) { union { unsigned u; __half2 h; } c; c.h = h; return c.u; }

struct F8 { float4 a, b; };
__device__ inline F8 ld8(const float* p) {
    F8 r; r.a = *(const float4*)p; r.b = *(const float4*)(p + 4); return r;
}
__device__ inline void gsample8(const float* base, const Bil& bl, float out[8]) {
    F8 v00 = ld8(base + (size_t)bl.i00*8);
    F8 v01 = ld8(base + (size_t)bl.i01*8);
    F8 v10 = ld8(base + (size_t)bl.i10*8);
    F8 v11 = ld8(base + (size_t)bl.i11*8);
    const float* p00 = (const float*)&v00;
    const float* p01 = (const float*)&v01;
    const float* p10 = (const float*)&v10;
    const float* p11 = (const float*)&v11;
    #pragma unroll
    for (int i = 0; i < 8; i++)
        out[i] = bl.w00*p00[i] + bl.w01*p01[i] + bl.w10*p10[i] + bl.w11*p11[i];
}

// K0: transpose feat (NCHW f32) -> featT (N,px,c) fp16.
__global__ __launch_bounds__(256) void nhwc_kernel(
        const float* __restrict__ feat, unsigned short* __restrict__ featT) {
    __shared__ unsigned short T[64*TLD];   // 34 KB
    int b = blockIdx.x >> 6, p0 = (blockIdx.x & 63)*64;
    int t = threadIdx.x;
    int x = t & 63, c4 = t >> 6;
    const float* fb = feat + (size_t)b*CC*HW + p0;
    #pragma unroll 4
    for (int cp = 0; cp < 256; cp += 4) {
        int c = cp + c4;
        T[x*TLD + c] = f2h(fb[(size_t)c*HW + x]);
    }
    __syncthreads();
    int xq = t >> 5, cl = t & 31;
    unsigned short* dst = featT + ((size_t)b*HW + p0)*256;
    #pragma unroll
    for (int w = 0; w < 8; w++) {
        int xr = w*8 + xq;
        *(uint4*)(dst + (size_t)xr*256 + cl*8) = *(const uint4*)(T + xr*TLD + cl*8);
    }
}

// K1a: pack dcn_off_w into MFMA A-fragment order, fp16.
__global__ void cpack_kernel(const float* __restrict__ w, short* __restrict__ Ap) {
    int idx = blockIdx.x*256 + threadIdx.x;   // 9216
    if (idx >= 9*2*8*64) return;
    int l  = idx & 63;
    int cs = (idx >> 6) & 7;
    int mt = (idx >> 9) & 1;
    int k  = idx >> 10;
    int oc = mt*16 + (l & 15);
    int c0 = cs*32 + (l >> 4)*8;
    short* dst = Ap + (size_t)idx*8;
    #pragma unroll
    for (int i = 0; i < 8; i++) {
        float v = (oc < 27) ? w[((size_t)(oc*256 + c0 + i)*3 + k/3)*3 + (k % 3)] : 0.f;
        dst[i] = (short)f2h(v);
    }
}

// K1b: pack dcn_w into MFMA fragment order, fp16 (A operand).
__global__ void wpack_kernel(const float* __restrict__ w, short* __restrict__ Wp) {
    int idx = blockIdx.x*256 + threadIdx.x;   // 73728
    if (idx >= 9*8*16*64) return;
    int l  = idx & 63;
    int ot = (idx >> 6) & 15;
    int cs = (idx >> 10) & 7;
    int k  = idx >> 13;
    int oc = ot*16 + (l & 15);
    int c0 = cs*32 + (l >> 4)*8;
    short* dst = Wp + (size_t)idx*8;
    #pragma unroll
    for (int i = 0; i < 8; i++) {
        float v = w[((size_t)(oc*256 + c0 + i)*3 + k/3)*3 + (k % 3)];
        dst[i] = (short)f2h(v);
    }
}

// K1c: pack the four 1x1-conv weights into MFMA A-fragment order (320 oc, bf16).
__global__ void wpack4_kernel(const float* __restrict__ so_w, const float* __restrict__ sc_w,
        const float* __restrict__ uw_w, const float* __restrict__ uo_w,
        short* __restrict__ Wc) {
    int idx = blockIdx.x*256 + threadIdx.x;   // 10240
    if (idx >= 8*20*64) return;
    int l  = idx & 63;
    int ot = (idx >> 6) % 20;
    int cs = idx / (64*20);
    int g  = ot*16 + (l & 15);
    int c0 = cs*32 + (l >> 4)*8;
    const float* src = nullptr; int oc = 0;
    if (g < 136)      { src = so_w; oc = g; }
    else if (g < 187) { src = sc_w; oc = g - 136; }
    else if (g < 238) { src = uw_w; oc = g - 187; }
    else if (g < 289) { src = uo_w; oc = g - 238; }
    short* dst = Wc + (size_t)idx*8;
    #pragma unroll
    for (int i = 0; i < 8; i++)
        dst[i] = src ? (short)f2bf(src[(size_t)oc*256 + c0 + i]) : (short)0;
}

// K2: FUSED conv3x3 (-> offL in LDS) + DCNv2 (R13 structure).
// 512 thr / 8 waves, grid 512, 2 blocks/CU. LDS: strip 53.9 KB (dcn S aliases)
// + offL 7 KB.
__global__ __launch_bounds__(512, 2) void dcn_kernel(
        const unsigned short* __restrict__ featT, const short* __restrict__ Ap,
        const float* __restrict__ cbias, const short* __restrict__ Wp,
        unsigned short* __restrict__ dcn16) {
    __shared__ __align__(16) short LB[3*66*CST];   // 53.9 KB conv strip; dcn S aliases
    __shared__ float offL[27*66];                  // 7 KB per-row off27

    int orig = blockIdx.x;                 // 512 blocks
    int blk  = (orig & 7)*64 + (orig >> 3);   // XCD swizzle: xcd == batch
    int b   = blk >> 6;
    int row = blk & 63;

    int t   = threadIdx.x;
    int l   = t & 63, wv = t >> 6;

    const unsigned short* fT = featT + (size_t)b*HW*256;

    // ---- conv3x3 phase: off27 for this row -> offL ----
    {
        int cmt = wv >> 2, cnt = wv & 3;   // oc-tile, px-tile
        f32x4 cacc = (f32x4){0.f,0.f,0.f,0.f};
        for (int ch = 0; ch < 2; ch++) {
            if (ch) __syncthreads();       // protect strip before restage
            for (int i = t; i < 3*66*16; i += 512) {
                int cc = i & 15;
                int rp = i >> 4;
                int r = rp / 66, px_s = rp - r*66;
                int yy = row + r - 1;
                int xx = px_s - 1;
                uint4 v = (uint4){0u,0u,0u,0u};
                if ((unsigned)yy < 64u && (unsigned)xx < 64u)
                    v = *(const uint4*)(fT + ((size_t)(yy*64 + xx))*256 + ch*128 + cc*8);
                *(uint4*)(&LB[(r*66 + px_s)*CST + cc*8]) = v;
            }
            __syncthreads();
            #pragma unroll
            for (int k = 0; k < 9; k++) {
                int ky = k/3, kx = k%3;
                const short* srow = LB + (ky*66 + cnt*16 + (l & 15) + kx)*CST + (l >> 4)*8;
                #pragma unroll
                for (int csl = 0; csl < 4; csl++) {
                    f16x8 bfrag = *(const f16x8*)(srow + csl*32);
                    const short* ap = Ap + ((size_t)((k*2 + cmt)*8 + ch*4 + csl)*64 + l)*8;
                    f16x8 a = *(const f16x8*)ap;
                    cacc = __builtin_amdgcn_mfma_f32_16x16x32_f16(a, bfrag, cacc, 0, 0, 0);
                }
            }
        }
        #pragma unroll
        for (int r = 0; r < 4; r++) {
            int oc = cmt*16 + (l >> 4)*4 + r;
            if (oc < 27)
                offL[oc*66 + cnt*16 + (l & 15)] = cacc[r] + cbias[oc];
        }
        __syncthreads();   // offL ready; strip reads done (S may now overwrite LB)
    }

    // ---- DCN phase (R13 structure; offsets from offL) ----
    short* S = LB;                         // 33.8 KB within strip space
    int pxh = t >> 4;          // 0..31
    int cl  = t & 15;          // 8-ch chunk

    f32x4 acc[2][4];
    #pragma unroll
    for (int i = 0; i < 2; i++)
        #pragma unroll
        for (int j = 0; j < 4; j++) acc[i][j] = (f32x4){0.f,0.f,0.f,0.f};

    for (int k = 0; k < 9; k++) {
        int kx = k % 3 - 1, ky = k / 3 - 1;
        #pragma unroll
        for (int pp = 0; pp < 2; pp++) {
            int px = pp*32 + pxh;
            float dyv = offL[k*66 + px];
            float dxv = offL[(9 + k)*66 + px];
            float mk  = offL[(18 + k)*66 + px];
            float m = 1.f/(1.f + expf(-mk));
            Bil bl = bilin((float)(px + kx) + dxv, (float)(row + ky) + dyv);
            __half2 h00 = __float2half2_rn(bl.w00*m);
            __half2 h01 = __float2half2_rn(bl.w01*m);
            __half2 h10 = __float2half2_rn(bl.w10*m);
            __half2 h11 = __float2half2_rn(bl.w11*m);
            #pragma unroll
            for (int cp = 0; cp < 2; cp++) {
                int c0 = cp*128 + cl*8;
                uint4 u00 = *(const uint4*)(fT + (size_t)bl.i00*256 + c0);
                uint4 u01 = *(const uint4*)(fT + (size_t)bl.i01*256 + c0);
                uint4 u10 = *(const uint4*)(fT + (size_t)bl.i10*256 + c0);
                uint4 u11 = *(const uint4*)(fT + (size_t)bl.i11*256 + c0);
                const unsigned* a00 = (const unsigned*)&u00;
                const unsigned* a01 = (const unsigned*)&u01;
                const unsigned* a10 = (const unsigned*)&u10;
                const unsigned* a11 = (const unsigned*)&u11;
                uint4 outp;
                unsigned* op = (unsigned*)&outp;
                #pragma unroll
                for (int q = 0; q < 4; q++) {
                    __half2 r = __hmul2(h11, u2h2(a11[q]));
                    r = __hfma2(h10, u2h2(a10[q]), r);
                    r = __hfma2(h01, u2h2(a01[q]), r);
                    r = __hfma2(h00, u2h2(a00[q]), r);
                    op[q] = h22u(r);
                }
                *(uint4*)(S + px*SLD + c0) = outp;
            }
        }
        __syncthreads();

        const short* wpk = Wp + (size_t)k*8*16*64*8;
        for (int cs = 0; cs < 8; cs++) {
            f16x8 wa[2];
            #pragma unroll
            for (int mt = 0; mt < 2; mt++)
                wa[mt] = *(const f16x8*)(wpk + ((size_t)((cs*16 + (wv*2 + mt))*64 + l))*8);
            f16x8 sb[4];
            #pragma unroll
            for (int pt = 0; pt < 4; pt++)
                sb[pt] = *(const f16x8*)(S + (pt*16 + (l & 15))*SLD
                                            + cs*32 + (l >> 4)*8);
            #pragma unroll
            for (int mt = 0; mt < 2; mt++)
                #pragma unroll
                for (int pt = 0; pt < 4; pt++)
                    acc[mt][pt] = __builtin_amdgcn_mfma_f32_16x16x32_f16(
                        wa[mt], sb[pt], acc[mt][pt], 0, 0, 0);
        }
        __syncthreads();
    }

    #pragma unroll
    for (int mt = 0; mt < 2; mt++)
        #pragma unroll
        for (int pt = 0; pt < 4; pt++)
            #pragma unroll
            for (int r = 0; r < 4; r++) {
                int oc = wv*32 + mt*16 + (l >> 4)*4 + r;
                int px = pt*16 + (l & 15);
                dcn16[((size_t)(b*256 + oc))*HW + row*64 + px] = f2bf(acc[mt][pt][r]);
            }
}

// K3: GroupNorm partial sums from bf16 dcn: 1024 blocks, 2 channels each.
__global__ __launch_bounds__(256) void gn_partial_kernel(
        const unsigned short* __restrict__ dcn16, float* __restrict__ partial) {
    int blk = blockIdx.x;
    const uint4* base = (const uint4*)(dcn16 + (size_t)blk*2*HW);
    float s = 0.f, s2 = 0.f;
    #pragma unroll
    for (int j = 0; j < 4; j++) {
        uint4 v = base[threadIdx.x + j*256];
        const unsigned* u = (const unsigned*)&v;
        #pragma unroll
        for (int q = 0; q < 4; q++) {
            float lo = bflo(u[q]), hi = bfhi(u[q]);
            s += lo + hi; s2 += lo*lo + hi*hi;
        }
    }
    __shared__ float rs[256], rs2[256];
    rs[threadIdx.x] = s; rs2[threadIdx.x] = s2; __syncthreads();
    for (int o = 128; o > 0; o >>= 1) {
        if (threadIdx.x < o) { rs[threadIdx.x] += rs[threadIdx.x+o]; rs2[threadIdx.x] += rs2[threadIdx.x+o]; }
        __syncthreads();
    }
    if (threadIdx.x == 0) { partial[blk*2] = rs[0]; partial[blk*2+1] = rs2[0]; }
}

// K5: fused GN-apply + residual (-> out_feat) + 1x1 convs + offset blend.
// 1024 blocks x 32 px, 512 thr / 8 waves, 17 KB LDS -> 4 blocks/CU.
__global__ __launch_bounds__(512, 4) void fused_tail_kernel(
        const float* __restrict__ feat, const unsigned short* __restrict__ dcn16,
        const float* __restrict__ partial, const float* __restrict__ gn_g,
        const float* __restrict__ gn_b, const short* __restrict__ Wc,
        const float* __restrict__ so_b, const float* __restrict__ sc_b,
        const float* __restrict__ uw_b, const float* __restrict__ uo_b,
        const float* __restrict__ prev_off,
        float* __restrict__ out_feat, float* __restrict__ SO,
        float* __restrict__ UC) {
    __shared__ __align__(16) short S[32*SLDF];  // 17 KB; overlaid by U after GEMM
    __shared__ float gstat[32][2];
    float* U = (float*)S;                       // [102][32] floats = 13 KB

    int orig = blockIdx.x;                      // 1024 blocks
    int swz = (orig & 7)*128 + (orig >> 3);     // XCD swizzle
    int b = swz >> 7;
    int half = swz & 127;
    int row = half >> 1, px0 = (half & 1)*32;
    int t = threadIdx.x;

    if (t < 32) {
        const float* pp = partial + (size_t)(b*32 + t)*8;
        float s  = pp[0] + pp[2] + pp[4] + pp[6];
        float s2 = pp[1] + pp[3] + pp[5] + pp[7];
        float inv = 1.f/(8.f*HW);
        float mu = s*inv;
        float var = s2*inv - mu*mu;
        gstat[t][0] = mu;
        gstat[t][1] = rsqrtf(var + 1e-5f);
    }
    __syncthreads();

    int x = t & 31, cq = t >> 5;                // 16 c-groups of 16 channels
    int l = t & 63, wv = t >> 6;
    const float* fb = feat + (size_t)b*CC*HW + row*64 + px0;
    const unsigned short* db = dcn16 + (size_t)b*CC*HW + row*64 + px0;
    float* ob = out_feat + (size_t)b*CC*HW + row*64 + px0;
    #pragma unroll
    for (int j = 0; j < 4; j++) {
        int c0 = cq*16 + j*4;
        float fv[4];
        #pragma unroll
        for (int q = 0; q < 4; q++) {
            int c = c0 + q;
            float mu = gstat[c >> 3][0], rstd = gstat[c >> 3][1];
            float v = (bf2f(db[(size_t)c*HW + x]) - mu)*rstd*gn_g[c] + gn_b[c];
            fv[q] = fb[(size_t)c*HW + x] + fmaxf(v, 0.f);
            ob[(size_t)c*HW + x] = fv[q];
        }
        uint2 pk;
        pk.x = cvt_pk_bf16(fv[0], fv[1]);
        pk.y = cvt_pk_bf16(fv[2], fv[3]);
        *(uint2*)(S + x*SLDF + c0) = pk;
    }
    __syncthreads();

    f32x4 acc[3][2];
    #pragma unroll
    for (int j = 0; j < 3; j++)
        #pragma unroll
        for (int pt = 0; pt < 2; pt++) acc[j][pt] = (f32x4){0.f,0.f,0.f,0.f};

    for (int cs = 0; cs < 8; cs++) {
        bf16x8 bg[2];
        #pragma unroll
        for (int pt = 0; pt < 2; pt++)
            bg[pt] = *(const bf16x8*)(S + (pt*16 + (l & 15))*SLDF
                                        + cs*32 + (l >> 4)*8);
        #pragma unroll
        for (int j = 0; j < 3; j++) {
            int tile = wv + j*8;
            if (tile < 20) {
                bf16x8 a = *(const bf16x8*)(Wc + ((size_t)(cs*20 + tile)*64 + l)*8);
                #pragma unroll
                for (int pt = 0; pt < 2; pt++)
                    acc[j][pt] = __builtin_amdgcn_mfma_f32_16x16x32_bf16(
                        a, bg[pt], acc[j][pt], 0, 0, 0);
            }
        }
    }
    __syncthreads();   // S dead; U live

    #pragma unroll
    for (int j = 0; j < 3; j++) {
        int tile = wv + j*8;
        if (tile < 20) {
            #pragma unroll
            for (int pt = 0; pt < 2; pt++) {
                int px = pt*16 + (l & 15);
                int p = row*64 + px0 + px;
                #pragma unroll
                for (int r = 0; r < 4; r++) {
                    int oc = tile*16 + (l >> 4)*4 + r;
                    float v = acc[j][pt][r];
                    if (oc < 136) {
                        SO[(((size_t)(b*JJ + (oc >> 3))*HW) + p)*8 + (oc & 7)] = v + so_b[oc];
                    } else if (oc < 187) {
                        int o2 = oc - 136;
                        int jj = o2/3, d = o2 - jj*3;
                        UC[(((size_t)(b*JJ + jj)*HW) + p)*8 + 3 + d] = v + sc_b[o2];
                    } else if (oc < 238) {
                        U[(oc-187)*32 + px] = v + uw_b[oc-187];
                    } else if (oc < 289) {
                        U[(51 + oc-238)*32 + px] = v + uo_b[oc-238];
                    }
                }
            }
        }
    }
    __syncthreads();

    const float* pb = prev_off + (size_t)b*51*HW + row*64 + px0;
    for (int i = t; i < 51*32; i += 512) {
        int dful = i >> 5, px = i & 31;
        int jj = dful/3, d = dful - jj*3;
        int p = row*64 + px0 + px;
        float owv = 1.f/(1.f + expf(-U[dful*32 + px]));
        float blend = (1.f - owv)*pb[(size_t)dful*HW + px] + owv*U[(51 + dful)*32 + px];
        UC[(((size_t)(b*JJ + jj)*HW) + p)*8 + d] = blend;
    }
}

// K7: fused sampling + softmax-weighted sum -> new_off (output 1).
__global__ __launch_bounds__(256) void final_kernel(
        const float* __restrict__ UC, const float* __restrict__ SO,
        float* __restrict__ out_off) {
    int orig = blockIdx.x;                   // 0..2175
    int wg = (orig & 7)*272 + (orig >> 3);   // 272 = 17*16 per batch
    int b = wg / 272;
    int rem = wg - b*272;
    int j = rem >> 4;
    int p = (rem & 15)*256 + threadIdx.x;
    int y = p >> 6, x = p & 63;
    const float* ucb = UC + (size_t)(b*JJ + j)*HW*8;
    const float* sob = SO + (size_t)(b*JJ + j)*HW*8;

    float4 own = *(const float4*)(ucb + (size_t)p*8);
    float offx = own.x, offy = own.y;
    F8 sod = ld8(sob + (size_t)p*8);
    const float* sodp = (const float*)&sod;

    Bil bl = bilin((float)x + offx, (float)y + offy);
    float s8[8];
    gsample8(sob, bl, s8);

    float sall[8][2];
    #pragma unroll
    for (int h = 0; h < 4; h++) {
        sall[h][0]   = s8[2*h]   + offx;
        sall[h][1]   = s8[2*h+1] + offy;
        sall[4+h][0] = sodp[2*h];
        sall[4+h][1] = sodp[2*h+1];
    }

    float sv[8][3], lg[8][3];
    #pragma unroll
    for (int n = 0; n < 8; n++) {
        Bil b2 = bilin((float)x + sall[n][0], (float)y + sall[n][1]);
        float v8[8];
        gsample8(ucb, b2, v8);
        #pragma unroll
        for (int d = 0; d < 3; d++) {
            sv[n][d] = v8[d];
            lg[n][d] = v8[3 + d];
        }
        sv[n][0] += sall[n][0];
        sv[n][1] += sall[n][1];
    }
    #pragma unroll
    for (int d = 0; d < 3; d++) {
        float m = lg[0][d];
        #pragma unroll
        for (int n = 1; n < 8; n++) m = fmaxf(m, lg[n][d]);
        float den = 0.f, num = 0.f;
        #pragma unroll
        for (int n = 0; n < 8; n++) {
            float e = expf(lg[n][d]-m);
            den += e; num += e*sv[n][d];
        }
        out_off[((size_t)b*51 + j*3 + d)*HW + p] = num/den;
    }
}

extern "C" void kernel_launch(void* const* d_in, const int* in_sizes, int n_in,
                              void* d_out, int out_size, void* d_ws, size_t ws_size,
                              hipStream_t stream) {
    const float* feat       = (const float*)d_in[0];
    const float* prev_off   = (const float*)d_in[1];
    const float* dcn_off_w  = (const float*)d_in[2];
    const float* dcn_off_b  = (const float*)d_in[3];
    const float* dcn_w      = (const float*)d_in[4];
    const float* gn_g       = (const float*)d_in[5];
    const float* gn_b       = (const float*)d_in[6];
    const float* so_w       = (const float*)d_in[7];
    const float* so_b       = (const float*)d_in[8];
    const float* sc_w       = (const float*)d_in[9];
    const float* sc_b       = (const float*)d_in[10];
    const float* uw_w       = (const float*)d_in[11];
    const float* uw_b       = (const float*)d_in[12];
    const float* uo_w       = (const float*)d_in[13];
    const float* uo_b       = (const float*)d_in[14];

    float* ws = (float*)d_ws;
    float* off27     = ws;                       // (unused now; layout kept)
    float* Wt        = off27 + 884736;           // pack region
    short* Wp        = (short*)Wt;               // 589824 shorts (dcn weights, fp16)
    short* Ap        = Wp + 589824;              // 73728 shorts (conv3x3 weights, fp16)
    short* Wc        = Ap + 73728;               // 81920 shorts (1x1 weights, bf16)
    float* dcnreg    = Wt + 589824;              // 8388608-float region
    unsigned short* dcn16 = (unsigned short*)dcnreg;   // 8.4M ushorts (bf16)
    float* partial   = dcnreg + 8388608;         // 2048
    float* SO        = partial + 2048;           // 4456448 (8*17*4096*8)
    float* UC        = SO + 4456448;             // 4456448

    // featT aliases SO (dead after dcn_kernel; SO written by fused_tail)
    unsigned short* featT = (unsigned short*)SO;

    float* out_feat = (float*)d_out;             // 8388608
    float* out_off  = out_feat + 8388608;        // 1671168

    // K0: NCHW f32 -> NHWC fp16 transpose
    nhwc_kernel<<<dim3(BB*64), dim3(256), 0, stream>>>(feat, featT);
    // packs
    cpack_kernel<<<dim3(36), dim3(256), 0, stream>>>(dcn_off_w, Ap);
    wpack_kernel<<<dim3(288), dim3(256), 0, stream>>>(dcn_w, Wp);
    wpack4_kernel<<<dim3(40), dim3(256), 0, stream>>>(so_w, sc_w, uw_w, uo_w, Wc);
    // K2: FUSED conv3x3 + DCN
    dcn_kernel<<<dim3(BB*64), dim3(512), 0, stream>>>(featT, Ap, dcn_off_b, Wp, dcn16);
    // K3: GroupNorm partials (bf16 input)
    gn_partial_kernel<<<dim3(1024), dim3(256), 0, stream>>>(dcn16, partial);
    // K5: fused GN + residual + 1x1 convs + offset blend (1024 x 32px blocks)
    fused_tail_kernel<<<dim3(1024), dim3(512), 0, stream>>>(feat, dcn16, partial,
        gn_g, gn_b, Wc, so_b, sc_b, uw_b, uo_b, prev_off,
        out_feat, SO, UC);
    // K7: fused double grid-sample + softmax reduction (packed gathers)
    final_kernel<<<dim3(2176), dim3(256), 0, stream>>>(UC, SO, out_off);
}